// Round 4
// baseline (224.167 us; speedup 1.0000x reference)
//
#include <hip/hip_runtime.h>
#include <hip/hip_bf16.h>
#include <stdint.h>

#define MDIM 8192
#define KDIM 1024
#define NDIM 1024
#define NEXP 8
#define WTM 64            // per-wave m-tile
#define WTN 64            // per-wave n-tile
#define NTN (NDIM / WTN)  // 16 n-tiles
#define LDSS 40           // fallback-kernel LDS stride

typedef __attribute__((ext_vector_type(8))) short bf16x8;
typedef __attribute__((ext_vector_type(4))) float floatx4;
typedef __attribute__((ext_vector_type(8))) unsigned short ushort8;

static __device__ __forceinline__ unsigned short f2b(float f) {
    // fp32 -> bf16 round-to-nearest-even (inputs finite)
    unsigned int u = __float_as_uint(f);
    return (unsigned short)((u + 0x7fffu + ((u >> 16) & 1u)) >> 16);
}

// ---------------- pass 1: fp32 -> bf16 (a and b) into workspace ----------------
// 16,777,216 elems, 8/thread -> 8192 blocks x 256 (exact). ~128 MB traffic, HBM floor ~20 us.
__global__ __launch_bounds__(256)
void cvt_bf16(const float* __restrict__ a, const float* __restrict__ b,
              unsigned short* __restrict__ wa, unsigned short* __restrict__ wb)
{
    const long t  = (long)blockIdx.x * 256 + threadIdx.x;
    const long NA = (long)MDIM * KDIM / 8;
    const float* src; unsigned short* dst; long v;
    if (t < NA) { src = a; dst = wa; v = t; }
    else        { src = b; dst = wb; v = t - NA; }
    const float4 lo = ((const float4*)src)[2 * v];
    const float4 hi = ((const float4*)src)[2 * v + 1];
    ushort8 o;
    o[0] = f2b(lo.x); o[1] = f2b(lo.y); o[2] = f2b(lo.z); o[3] = f2b(lo.w);
    o[4] = f2b(hi.x); o[5] = f2b(hi.y); o[6] = f2b(hi.z); o[7] = f2b(hi.w);
    ((ushort8*)dst)[v] = o;
}

// ---------------- pass 2: barrier-free register GEMM ---------------------------
// Each wave owns a 64x64 tile. A/B fragments for mfma_f32_16x16x32_bf16 are
// 8 contiguous bf16 at [row = lane&15, k = quad*8] -> one global_load_dwordx4
// per lane, straight to VGPRs. No LDS, no __syncthreads: compiler is free to
// interleave MFMA with in-flight loads using fine-grained vmcnt(N).
__global__ __launch_bounds__(256, 2)
void grouped_gemm_reg(const unsigned short* __restrict__ A,   // [M,K] bf16
                      const unsigned short* __restrict__ B,   // [E,N,K] bf16
                      const int* __restrict__ seg_indptr,
                      const int* __restrict__ widx,
                      float* __restrict__ c)
{
    const int wave = (int)threadIdx.x >> 6;
    const int lane = (int)threadIdx.x & 63;
    const int tile = (int)blockIdx.x * 4 + wave;

    // tile -> (segment, m0, n0); n-tile fastest so a block's 4 waves share A rows (L1)
    int rem = tile;
    int s = -1, m0 = 0, seg_end = 0, n0 = 0;
    for (int i = 0; i < NEXP; ++i) {
        int ps = seg_indptr[i], pe = seg_indptr[i + 1];
        int nt = ((pe - ps + WTM - 1) / WTM) * NTN;
        if (rem < nt) { s = i; m0 = ps + (rem / NTN) * WTM; n0 = (rem % NTN) * WTN; seg_end = pe; break; }
        rem -= nt;
    }
    if (s < 0) return;  // surplus wave (worst-case grid)

    const unsigned short* __restrict__ be = B + (size_t)widx[s] * (size_t)(NDIM * KDIM);
    const int fr   = lane & 15;
    const int quad = lane >> 4;

    // 8 per-lane row pointers (A rows clamped; stores masked by seg_end in epilogue)
    const unsigned short* ap[4];
    const unsigned short* bp[4];
#pragma unroll
    for (int i = 0; i < 4; ++i) {
        int ra = m0 + i * 16 + fr; if (ra >= MDIM) ra = MDIM - 1;
        ap[i] = A  + (size_t)ra * KDIM + quad * 8;
        bp[i] = be + (size_t)(n0 + i * 16 + fr) * KDIM + quad * 8;
    }

    floatx4 acc[4][4] = {};
    bf16x8 af[2][4], bf[2][4];

    // prologue: k=0 fragments into buf0
#pragma unroll
    for (int i = 0; i < 4; ++i) {
        af[0][i] = *reinterpret_cast<const bf16x8*>(ap[i]);
        bf[0][i] = *reinterpret_cast<const bf16x8*>(bp[i]);
    }

    for (int k0 = 0; k0 < KDIM; k0 += 64) {   // 16 iters, 2 k-slabs each
        // prefetch k0+32 into buf1, compute buf0
#pragma unroll
        for (int i = 0; i < 4; ++i) {
            af[1][i] = *reinterpret_cast<const bf16x8*>(ap[i] + k0 + 32);
            bf[1][i] = *reinterpret_cast<const bf16x8*>(bp[i] + k0 + 32);
        }
#pragma unroll
        for (int mi = 0; mi < 4; ++mi)
#pragma unroll
            for (int ni = 0; ni < 4; ++ni)
                acc[mi][ni] = __builtin_amdgcn_mfma_f32_16x16x32_bf16(af[0][mi], bf[0][ni], acc[mi][ni], 0, 0, 0);

        // prefetch k0+64 into buf0 (branchless wrap -> dummy reload of k=0 on last), compute buf1
        const int kn = (k0 + 64 < KDIM) ? (k0 + 64) : 0;
#pragma unroll
        for (int i = 0; i < 4; ++i) {
            af[0][i] = *reinterpret_cast<const bf16x8*>(ap[i] + kn);
            bf[0][i] = *reinterpret_cast<const bf16x8*>(bp[i] + kn);
        }
#pragma unroll
        for (int mi = 0; mi < 4; ++mi)
#pragma unroll
            for (int ni = 0; ni < 4; ++ni)
                acc[mi][ni] = __builtin_amdgcn_mfma_f32_16x16x32_bf16(af[1][mi], bf[1][ni], acc[mi][ni], 0, 0, 0);
    }

    // epilogue: C/D layout col=lane&15, row=quad*4+reg (m89-verified); mask partial rows
#pragma unroll
    for (int mi = 0; mi < 4; ++mi) {
        const int rbase = m0 + mi * 16 + quad * 4;
#pragma unroll
        for (int ni = 0; ni < 4; ++ni) {
            const int col = n0 + ni * 16 + fr;
#pragma unroll
            for (int j = 0; j < 4; ++j) {
                const int row = rbase + j;
                if (row < seg_end)
                    c[(size_t)row * NDIM + col] = acc[mi][ni][j];
            }
        }
    }
}

// ---------------- fallback (R1 fused kernel) if workspace is too small ----------
__global__ __launch_bounds__(256, 2)
void grouped_gemm_fused(const float* __restrict__ a, const float* __restrict__ b,
                        const int* __restrict__ seg_indptr, const int* __restrict__ widx,
                        float* __restrict__ c)
{
    __shared__ unsigned short Asf[128 * LDSS];
    __shared__ unsigned short Bsf[128 * LDSS];
    const int NT = NDIM / 128;
    int rem = (int)blockIdx.x;
    int s = -1, m0 = 0, seg_end = 0, n0 = 0;
    for (int i = 0; i < NEXP; ++i) {
        int ps = seg_indptr[i], pe = seg_indptr[i + 1];
        int nt = ((pe - ps + 127) / 128) * NT;
        if (rem < nt) { s = i; m0 = ps + (rem / NT) * 128; n0 = (rem % NT) * 128; seg_end = pe; break; }
        rem -= nt;
    }
    if (s < 0) return;
    const float* __restrict__ be = b + (size_t)widx[s] * (size_t)(NDIM * KDIM);
    const int tid = (int)threadIdx.x;
    const int r0 = tid >> 3;
    const int kc = (tid & 7) * 4;
    int arow[4];
#pragma unroll
    for (int u = 0; u < 4; ++u) {
        int r = m0 + r0 + 32 * u;
        arow[u] = r < MDIM ? r : MDIM - 1;
    }
    const int lane = tid & 63;
    const int wave = tid >> 6;
    const int wm = (wave & 1) * 64;
    const int wn = (wave >> 1) * 64;
    const int fr = lane & 15;
    const int quad = lane >> 4;
    floatx4 acc[4][4] = {};
    float4 av[4], bv[4];
#pragma unroll
    for (int u = 0; u < 4; ++u) {
        av[u] = *reinterpret_cast<const float4*>(a + (size_t)arow[u] * KDIM + kc);
        bv[u] = *reinterpret_cast<const float4*>(be + (size_t)(n0 + r0 + 32 * u) * KDIM + kc);
    }
    for (int k0 = 0; k0 < KDIM; k0 += 32) {
        __syncthreads();
#pragma unroll
        for (int u = 0; u < 4; ++u) {
            ushort4 ua, ub;
            ua.x = f2b(av[u].x); ua.y = f2b(av[u].y); ua.z = f2b(av[u].z); ua.w = f2b(av[u].w);
            ub.x = f2b(bv[u].x); ub.y = f2b(bv[u].y); ub.z = f2b(bv[u].z); ub.w = f2b(bv[u].w);
            *reinterpret_cast<ushort4*>(&Asf[(r0 + 32 * u) * LDSS + kc]) = ua;
            *reinterpret_cast<ushort4*>(&Bsf[(r0 + 32 * u) * LDSS + kc]) = ub;
        }
        const int kn = (k0 + 32 < KDIM) ? (k0 + 32) : 0;
#pragma unroll
        for (int u = 0; u < 4; ++u) {
            av[u] = *reinterpret_cast<const float4*>(a + (size_t)arow[u] * KDIM + kn + kc);
            bv[u] = *reinterpret_cast<const float4*>(be + (size_t)(n0 + r0 + 32 * u) * KDIM + kn + kc);
        }
        __syncthreads();
        bf16x8 af[4], bf[4];
#pragma unroll
        for (int mi = 0; mi < 4; ++mi)
            af[mi] = *reinterpret_cast<const bf16x8*>(&Asf[(wm + mi * 16 + fr) * LDSS + quad * 8]);
#pragma unroll
        for (int ni = 0; ni < 4; ++ni)
            bf[ni] = *reinterpret_cast<const bf16x8*>(&Bsf[(wn + ni * 16 + fr) * LDSS + quad * 8]);
#pragma unroll
        for (int mi = 0; mi < 4; ++mi)
#pragma unroll
            for (int ni = 0; ni < 4; ++ni)
                acc[mi][ni] = __builtin_amdgcn_mfma_f32_16x16x32_bf16(af[mi], bf[ni], acc[mi][ni], 0, 0, 0);
    }
#pragma unroll
    for (int mi = 0; mi < 4; ++mi) {
        const int rbase = m0 + wm + mi * 16 + quad * 4;
#pragma unroll
        for (int ni = 0; ni < 4; ++ni) {
            const int col = n0 + wn + ni * 16 + fr;
#pragma unroll
            for (int j = 0; j < 4; ++j) {
                const int row = rbase + j;
                if (row < seg_end)
                    c[(size_t)row * NDIM + col] = acc[mi][ni][j];
            }
        }
    }
}

extern "C" void kernel_launch(void* const* d_in, const int* in_sizes, int n_in,
                              void* d_out, int out_size, void* d_ws, size_t ws_size,
                              hipStream_t stream) {
    const float* a          = (const float*)d_in[0];
    const float* b          = (const float*)d_in[1];
    const int*   seg_indptr = (const int*)d_in[5];
    const int*   widx       = (const int*)d_in[6];
    float*       out        = (float*)d_out;

    const size_t need = (size_t)(MDIM + NEXP * NDIM) * KDIM * sizeof(unsigned short); // 32 MiB
    if (ws_size >= need) {
        unsigned short* wa = (unsigned short*)d_ws;                       // [M,K] bf16
        unsigned short* wb = wa + (size_t)MDIM * KDIM;                    // [E,N,K] bf16
        hipLaunchKernelGGL(cvt_bf16, dim3(8192), dim3(256), 0, stream, a, b, wa, wb);
        // worst-case tiles: (8192/64 + 7) row-tiles x 16 n-tiles = 2160 waves -> 540 blocks
        hipLaunchKernelGGL(grouped_gemm_reg, dim3(540), dim3(256), 0, stream,
                           wa, wb, seg_indptr, widx, out);
    } else {
        hipLaunchKernelGGL(grouped_gemm_fused, dim3(568), dim3(256), 0, stream,
                           a, b, seg_indptr, widx, out);
    }
}

// Round 5
// 163.995 us; speedup vs baseline: 1.3669x; 1.3669x over previous
//
#include <hip/hip_runtime.h>
#include <hip/hip_bf16.h>
#include <stdint.h>

#define MDIM 8192
#define KDIM 1024
#define NDIM 1024
#define NEXP 8
#define BM 128
#define BN 128
#define BK 64          // 16 K-iters, 32 MFMA/wave/iter, staging rows = full 128B lines
#define LDSS 40        // fallback-kernel LDS stride

typedef __attribute__((ext_vector_type(8))) short bf16x8;
typedef __attribute__((ext_vector_type(4))) float floatx4;
typedef __attribute__((ext_vector_type(8))) unsigned short ushort8;

static __device__ __forceinline__ unsigned short f2b(float f) {
    unsigned int u = __float_as_uint(f);
    return (unsigned short)((u + 0x7fffu + ((u >> 16) & 1u)) >> 16);
}

// ---------------- pass 1: fp32 -> bf16 (a and b) into workspace ----------------
__global__ __launch_bounds__(256)
void cvt_bf16(const float* __restrict__ a, const float* __restrict__ b,
              unsigned short* __restrict__ wa, unsigned short* __restrict__ wb)
{
    const long t  = (long)blockIdx.x * 256 + threadIdx.x;
    const long NA = (long)MDIM * KDIM / 8;
    const float* src; unsigned short* dst; long v;
    if (t < NA) { src = a; dst = wa; v = t; }
    else        { src = b; dst = wb; v = t - NA; }
    const float4 lo = ((const float4*)src)[2 * v];
    const float4 hi = ((const float4*)src)[2 * v + 1];
    ushort8 o;
    o[0] = f2b(lo.x); o[1] = f2b(lo.y); o[2] = f2b(lo.z); o[3] = f2b(lo.w);
    o[4] = f2b(hi.x); o[5] = f2b(hi.y); o[6] = f2b(hi.z); o[7] = f2b(hi.w);
    ((ushort8*)dst)[v] = o;
}

// ---------------- pass 2: bf16 GEMM, 128x128x64, dbuf LDS, swizzled chunks -----
#define GLDS(gp, lp) __builtin_amdgcn_global_load_lds(                        \
    (const __attribute__((address_space(1))) unsigned int*)(gp),              \
    (__attribute__((address_space(3))) unsigned int*)(lp), 16, 0, 0)

// LDS layout per buffer: [128 rows][64 bf16 = 8 chunks of 16B], chunk position
// p holds global chunk p ^ (row & 7)  (XOR swizzle -> conflict-free frag reads).
// Staging GLDS dest = wave-uniform base + lane*16B, which equals row-major order
// for row = j*32 + tid/8, pos = tid&7. Global chunk loaded = (tid&7) ^ (srow&7).

__global__ __launch_bounds__(256, 2)
void grouped_gemm_v5(const unsigned short* __restrict__ A,   // [M,K] bf16
                     const unsigned short* __restrict__ B,   // [E,N,K] bf16
                     const int* __restrict__ seg_indptr,
                     const int* __restrict__ widx,
                     float* __restrict__ c)
{
    __shared__ unsigned short As0[BM * BK], As1[BM * BK];   // 16KB each
    __shared__ unsigned short Bs0[BN * BK], Bs1[BN * BK];   // 64KB total -> 2 blocks/CU

    // XCD swizzle: 568 = 8*71; consecutive tiles (same segment/m-slab) land on one XCD
    const int bid = ((int)blockIdx.x & 7) * 71 + ((int)blockIdx.x >> 3);

    const int NTN = NDIM / BN;  // 8
    int rem = bid;
    int s = -1, m0 = 0, seg_end = 0, n0 = 0;
    for (int i = 0; i < NEXP; ++i) {
        int ps = seg_indptr[i], pe = seg_indptr[i + 1];
        int nt = ((pe - ps + BM - 1) / BM) * NTN;
        if (rem < nt) { s = i; m0 = ps + (rem / NTN) * BM; n0 = (rem % NTN) * BN; seg_end = pe; break; }
        rem -= nt;
    }
    if (s < 0) return;

    const unsigned short* __restrict__ be = B + (size_t)widx[s] * (size_t)(NDIM * KDIM);

    const int tid  = (int)threadIdx.x;
    const int wave = tid >> 6;
    const int lane = tid & 63;

    // staging geometry: call j stages rows [j*32, j*32+32); thread -> row j*32 + tid/8,
    // LDS pos tid&7, global chunk (tid&7)^(srow&7). Wave reads 8 rows x full 128B line.
    const int srow = tid >> 3;                       // 0..31
    const int gch  = ((tid & 7) ^ (srow & 7)) * 8;   // swizzled global chunk (bf16 offset)
    const unsigned short* ap[4];
    const unsigned short* bp[4];
#pragma unroll
    for (int j = 0; j < 4; ++j) {
        int ra = m0 + j * 32 + srow; if (ra >= MDIM) ra = MDIM - 1;  // clamp; masked at store
        ap[j] = A  + (size_t)ra * KDIM + gch;
        bp[j] = be + (size_t)(n0 + j * 32 + srow) * KDIM + gch;
    }
    const int ldso = wave * 512;   // + j*2048 elems; HW adds lane*16B

    const int wm = (wave & 1) * 64;
    const int wn = (wave >> 1) * 64;
    const int fr   = lane & 15;
    const int quad = lane >> 4;
    // frag read offsets within a row (elements), per k-half h: ((h*4+quad)^(fr&7))*8
    const int fro0 = ((0 * 4 + quad) ^ (fr & 7)) * 8;
    const int fro1 = ((1 * 4 + quad) ^ (fr & 7)) * 8;

    floatx4 acc[4][4] = {};

#define STAGE(AS, BS, kk)                                                     \
    do {                                                                      \
        _Pragma("unroll")                                                     \
        for (int j = 0; j < 4; ++j) {                                         \
            GLDS(ap[j] + (kk), &AS[j * 2048 + ldso]);                         \
            GLDS(bp[j] + (kk), &BS[j * 2048 + ldso]);                         \
        }                                                                     \
    } while (0)

#define COMPUTE(AS, BS)                                                       \
    do {                                                                      \
        bf16x8 af[4], bf[4];                                                  \
        _Pragma("unroll")                                                     \
        for (int h = 0; h < 2; ++h) {                                         \
            const int fro = h ? fro1 : fro0;                                  \
            _Pragma("unroll")                                                 \
            for (int mi = 0; mi < 4; ++mi)                                    \
                af[mi] = *reinterpret_cast<const bf16x8*>(                    \
                    &AS[(wm + mi * 16 + fr) * BK + fro]);                     \
            _Pragma("unroll")                                                 \
            for (int ni = 0; ni < 4; ++ni)                                    \
                bf[ni] = *reinterpret_cast<const bf16x8*>(                    \
                    &BS[(wn + ni * 16 + fr) * BK + fro]);                     \
            _Pragma("unroll")                                                 \
            for (int mi = 0; mi < 4; ++mi)                                    \
                _Pragma("unroll")                                             \
                for (int ni = 0; ni < 4; ++ni)                                \
                    acc[mi][ni] = __builtin_amdgcn_mfma_f32_16x16x32_bf16(    \
                        af[mi], bf[ni], acc[mi][ni], 0, 0, 0);                \
        }                                                                     \
    } while (0)

    STAGE(As0, Bs0, 0);                     // prologue: slab 0 -> buf0
#pragma unroll 1
    for (int ii = 0; ii < 8; ++ii) {
        const int i0 = ii * 2;
        __syncthreads();                    // drains buf0's loads (flew during prior compute)
        STAGE(As1, Bs1, (i0 + 1) * BK);     // slab i0+1 -> buf1 (i0 <= 14, always valid)
        COMPUTE(As0, Bs0);
        __syncthreads();                    // drains buf1's loads
        if (i0 + 2 < 16) STAGE(As0, Bs0, (i0 + 2) * BK);
        COMPUTE(As1, Bs1);
    }

    // epilogue: C/D layout col=lane&15, row=quad*4+reg (m89-verified); mask partial rows
#pragma unroll
    for (int mi = 0; mi < 4; ++mi) {
        const int rbase = m0 + wm + mi * 16 + quad * 4;
#pragma unroll
        for (int ni = 0; ni < 4; ++ni) {
            const int col = n0 + wn + ni * 16 + fr;
#pragma unroll
            for (int j = 0; j < 4; ++j) {
                const int row = rbase + j;
                if (row < seg_end)
                    c[(size_t)row * NDIM + col] = acc[mi][ni][j];
            }
        }
    }
#undef STAGE
#undef COMPUTE
}

// ---------------- fallback (R1 fused kernel) if workspace is too small ----------
__global__ __launch_bounds__(256, 2)
void grouped_gemm_fused(const float* __restrict__ a, const float* __restrict__ b,
                        const int* __restrict__ seg_indptr, const int* __restrict__ widx,
                        float* __restrict__ c)
{
    __shared__ unsigned short Asf[128 * LDSS];
    __shared__ unsigned short Bsf[128 * LDSS];
    const int NT = NDIM / 128;
    int rem = (int)blockIdx.x;
    int s = -1, m0 = 0, seg_end = 0, n0 = 0;
    for (int i = 0; i < NEXP; ++i) {
        int ps = seg_indptr[i], pe = seg_indptr[i + 1];
        int nt = ((pe - ps + 127) / 128) * NT;
        if (rem < nt) { s = i; m0 = ps + (rem / NT) * 128; n0 = (rem % NT) * 128; seg_end = pe; break; }
        rem -= nt;
    }
    if (s < 0) return;
    const float* __restrict__ be = b + (size_t)widx[s] * (size_t)(NDIM * KDIM);
    const int tid = (int)threadIdx.x;
    const int r0 = tid >> 3;
    const int kc = (tid & 7) * 4;
    int arow[4];
#pragma unroll
    for (int u = 0; u < 4; ++u) {
        int r = m0 + r0 + 32 * u;
        arow[u] = r < MDIM ? r : MDIM - 1;
    }
    const int lane = tid & 63;
    const int wave = tid >> 6;
    const int wm = (wave & 1) * 64;
    const int wn = (wave >> 1) * 64;
    const int fr = lane & 15;
    const int quad = lane >> 4;
    floatx4 acc[4][4] = {};
    float4 av[4], bv[4];
#pragma unroll
    for (int u = 0; u < 4; ++u) {
        av[u] = *reinterpret_cast<const float4*>(a + (size_t)arow[u] * KDIM + kc);
        bv[u] = *reinterpret_cast<const float4*>(be + (size_t)(n0 + r0 + 32 * u) * KDIM + kc);
    }
    for (int k0 = 0; k0 < KDIM; k0 += 32) {
        __syncthreads();
#pragma unroll
        for (int u = 0; u < 4; ++u) {
            ushort4 ua, ub;
            ua.x = f2b(av[u].x); ua.y = f2b(av[u].y); ua.z = f2b(av[u].z); ua.w = f2b(av[u].w);
            ub.x = f2b(bv[u].x); ub.y = f2b(bv[u].y); ub.z = f2b(bv[u].z); ub.w = f2b(bv[u].w);
            *reinterpret_cast<ushort4*>(&Asf[(r0 + 32 * u) * LDSS + kc]) = ua;
            *reinterpret_cast<ushort4*>(&Bsf[(r0 + 32 * u) * LDSS + kc]) = ub;
        }
        const int kn = (k0 + 32 < KDIM) ? (k0 + 32) : 0;
#pragma unroll
        for (int u = 0; u < 4; ++u) {
            av[u] = *reinterpret_cast<const float4*>(a + (size_t)arow[u] * KDIM + kn + kc);
            bv[u] = *reinterpret_cast<const float4*>(be + (size_t)(n0 + r0 + 32 * u) * KDIM + kn + kc);
        }
        __syncthreads();
        bf16x8 af[4], bf[4];
#pragma unroll
        for (int mi = 0; mi < 4; ++mi)
            af[mi] = *reinterpret_cast<const bf16x8*>(&Asf[(wm + mi * 16 + fr) * LDSS + quad * 8]);
#pragma unroll
        for (int ni = 0; ni < 4; ++ni)
            bf[ni] = *reinterpret_cast<const bf16x8*>(&Bsf[(wn + ni * 16 + fr) * LDSS + quad * 8]);
#pragma unroll
        for (int mi = 0; mi < 4; ++mi)
#pragma unroll
            for (int ni = 0; ni < 4; ++ni)
                acc[mi][ni] = __builtin_amdgcn_mfma_f32_16x16x32_bf16(af[mi], bf[ni], acc[mi][ni], 0, 0, 0);
    }
#pragma unroll
    for (int mi = 0; mi < 4; ++mi) {
        const int rbase = m0 + wm + mi * 16 + quad * 4;
#pragma unroll
        for (int ni = 0; ni < 4; ++ni) {
            const int col = n0 + wn + ni * 16 + fr;
#pragma unroll
            for (int j = 0; j < 4; ++j) {
                const int row = rbase + j;
                if (row < seg_end)
                    c[(size_t)row * NDIM + col] = acc[mi][ni][j];
            }
        }
    }
}

extern "C" void kernel_launch(void* const* d_in, const int* in_sizes, int n_in,
                              void* d_out, int out_size, void* d_ws, size_t ws_size,
                              hipStream_t stream) {
    const float* a          = (const float*)d_in[0];
    const float* b          = (const float*)d_in[1];
    const int*   seg_indptr = (const int*)d_in[5];
    const int*   widx       = (const int*)d_in[6];
    float*       out        = (float*)d_out;

    const size_t need = (size_t)(MDIM + NEXP * NDIM) * KDIM * sizeof(unsigned short); // 32 MiB
    if (ws_size >= need) {
        unsigned short* wa = (unsigned short*)d_ws;                       // [M,K] bf16
        unsigned short* wb = wa + (size_t)MDIM * KDIM;                    // [E,N,K] bf16
        hipLaunchKernelGGL(cvt_bf16, dim3(8192), dim3(256), 0, stream, a, b, wa, wb);
        // worst-case tiles: (64+7) row-tiles x 8 n-tiles = 568 = 8*71 (swizzle bijective)
        hipLaunchKernelGGL(grouped_gemm_v5, dim3(568), dim3(256), 0, stream,
                           wa, wb, seg_indptr, widx, out);
    } else {
        hipLaunchKernelGGL(grouped_gemm_fused, dim3(568), dim3(256), 0, stream,
                           a, b, seg_indptr, widx, out);
    }
}